// Round 6
// baseline (640.946 us; speedup 1.0000x reference)
//
#include <hip/hip_runtime.h>

#define BN_EPS 1e-5f

typedef _Float16 half_t;
typedef _Float16 half2_t __attribute__((ext_vector_type(2)));
typedef unsigned short ushort_t;

// ---------------- CSR build ----------------
__global__ void hist_kernel(const int* __restrict__ ei, int* __restrict__ deg,
                            ushort_t* __restrict__ rank, int E, int n) {
  int e = blockIdx.x * blockDim.x + threadIdx.x;
  if (e >= E + n) return;
  int d = (e < E) ? ei[E + e] : (e - E);
  rank[e] = (ushort_t)atomicAdd(&deg[d], 1);
}

__global__ void __launch_bounds__(256) block_sum_kernel(const int* __restrict__ deg,
                                                        int* __restrict__ bsum, int n) {
  __shared__ int ws[4];
  int base = blockIdx.x * 1024;
  int s = 0;
  for (int i = threadIdx.x; i < 1024; i += 256) {
    int idx = base + i;
    s += (idx < n) ? deg[idx] : 0;
  }
#pragma unroll
  for (int off = 32; off; off >>= 1) s += __shfl_down(s, off, 64);
  int lane = threadIdx.x & 63, wid = threadIdx.x >> 6;
  if (lane == 0) ws[wid] = s;
  __syncthreads();
  if (threadIdx.x == 0) bsum[blockIdx.x] = ws[0] + ws[1] + ws[2] + ws[3];
}

__global__ void __launch_bounds__(1024) scan_sums_kernel(int* __restrict__ bsum, int nb) {
  __shared__ int wsum[16];
  int tid = threadIdx.x, lane = tid & 63, wid = tid >> 6;
  int v = (tid < nb) ? bsum[tid] : 0;
  int incl = v;
#pragma unroll
  for (int off = 1; off < 64; off <<= 1) {
    int t = __shfl_up(incl, off, 64);
    if (lane >= off) incl += t;
  }
  if (lane == 63) wsum[wid] = incl;
  __syncthreads();
  if (wid == 0 && lane < 16) {
    int s = wsum[lane];
#pragma unroll
    for (int off = 1; off < 16; off <<= 1) {
      int t = __shfl_up(s, off, 16);
      if (lane >= off) s += t;
    }
    wsum[lane] = s;
  }
  __syncthreads();
  int woff = (wid > 0) ? wsum[wid - 1] : 0;
  if (tid < nb) bsum[tid] = incl + woff - v;  // exclusive
}

__global__ void __launch_bounds__(1024) scan_block_kernel(const int* __restrict__ deg,
                                                          const int* __restrict__ boff,
                                                          int* __restrict__ indptr, int n) {
  __shared__ int wsum[16];
  int tid = threadIdx.x, lane = tid & 63, wid = tid >> 6;
  int i = blockIdx.x * 1024 + tid;
  int v = (i < n) ? deg[i] : 0;
  int incl = v;
#pragma unroll
  for (int off = 1; off < 64; off <<= 1) {
    int t = __shfl_up(incl, off, 64);
    if (lane >= off) incl += t;
  }
  if (lane == 63) wsum[wid] = incl;
  __syncthreads();
  if (wid == 0 && lane < 16) {
    int s = wsum[lane];
#pragma unroll
    for (int off = 1; off < 16; off <<= 1) {
      int t = __shfl_up(s, off, 16);
      if (lane >= off) s += t;
    }
    wsum[lane] = s;
  }
  __syncthreads();
  int woff = (wid > 0) ? wsum[wid - 1] : 0;
  if (i < n) indptr[i + 1] = incl + woff + boff[blockIdx.x];
  if (i == 0) indptr[0] = 0;
}

__global__ void place_kernel(const int* __restrict__ ei, const ushort_t* __restrict__ rank,
                             const int* __restrict__ indptr, int* __restrict__ csrc,
                             int E, int n) {
  int e = blockIdx.x * blockDim.x + threadIdx.x;
  if (e >= E + n) return;
  int s, d;
  if (e < E) { s = ei[e]; d = ei[E + e]; } else { s = e - E; d = s; }
  __builtin_nontemporal_store(s, &csrc[indptr[d] + (int)rank[e]]);
}

// ---------------- node transform ----------------
// Each thread computes JT consecutive outputs j for one node.
// xl (fp16, padded [n][H][CPAD]) = x@Wl+bl ; xr (fp32, [n][HC]) = x@Wr+br

template <int CIN, int H, int C, int CPAD, int JT>
__global__ void __launch_bounds__(256) transform_kernel(
    const float* __restrict__ x, const float* __restrict__ Wl, const float* __restrict__ Wr,
    const float* __restrict__ bl, const float* __restrict__ br, half_t* __restrict__ xl,
    float* __restrict__ xr, int n) {
  constexpr int HC = H * C;
  constexpr int TPN = HC / JT;  // threads per node
  __shared__ float sW[2 * CIN * HC];
  for (int i = threadIdx.x; i < CIN * HC; i += blockDim.x) {
    sW[i] = Wl[i];
    sW[CIN * HC + i] = Wr[i];
  }
  __syncthreads();
  int idx = blockIdx.x * blockDim.x + threadIdx.x;
  if (idx >= n * TPN) return;
  int node = idx / TPN;
  int j0 = (idx - node * TPN) * JT;

  float al[JT], ar[JT];
#pragma unroll
  for (int jj = 0; jj < JT; jj++) {
    al[jj] = bl[j0 + jj];
    ar[jj] = br[j0 + jj];
  }
  const float2* xrow = reinterpret_cast<const float2*>(x + (size_t)node * CIN);
#pragma unroll
  for (int k2 = 0; k2 < CIN / 2; k2++) {
    float2 xv = xrow[k2];
#pragma unroll
    for (int q = 0; q < 2; q++) {
      float xs = q ? xv.y : xv.x;
      int k = 2 * k2 + q;
#pragma unroll
      for (int jj = 0; jj < JT; jj++) {
        al[jj] = fmaf(xs, sW[k * HC + j0 + jj], al[jj]);
        ar[jj] = fmaf(xs, sW[CIN * HC + k * HC + j0 + jj], ar[jj]);
      }
    }
  }
#pragma unroll
  for (int jj = 0; jj < JT; jj++) {
    int j = j0 + jj;
    int h = j / C, c = j - h * C;
    xl[((size_t)node * H + h) * CPAD + c] = (half_t)al[jj];
    xr[(size_t)node * HC + j] = ar[jj];
  }
}

// ---------------- fused edge pass ----------------
// Thread = (node, head, s) with s in [0,S): processes edges p0+s, p0+s+S, ...
// Partial (den, acc) combined across the S-group via __shfl_xor (in-wave).
// Depth-2 clamped-index pipeline. MODE 0: +bias,BN  1: +bias,BN,ELU  2: raw

#define ROW(B, IR)                                                                \
  {                                                                               \
    const uint4* xp_ = reinterpret_cast<const uint4*>(xlh + (size_t)(IR) * HCP);  \
    _Pragma("unroll") for (int i_ = 0; i_ < NB; i_++) B[i_] = xp_[i_];            \
  }

#define COMP_ROW(B, M)                                                                      \
  {                                                                                         \
    const half2_t* hp_ = reinterpret_cast<const half2_t*>(B);                               \
    float xs_[C];                                                                           \
    _Pragma("unroll") for (int i = 0; i < C / 2; i++) {                                     \
      xs_[2 * i] = (float)hp_[i].x;                                                         \
      xs_[2 * i + 1] = (float)hp_[i].y;                                                     \
    }                                                                                       \
    float e_ = 0.f;                                                                         \
    _Pragma("unroll") for (int c = 0; c < C; c++) {                                         \
      float m_ = xs_[c] + xr_reg[c];                                                        \
      m_ = (m_ > 0.f) ? m_ : 0.2f * m_;                                                     \
      e_ = fmaf(att_reg[c], m_, e_);                                                        \
    }                                                                                       \
    float ex_ = ((M) < cnt_s) ? __expf(e_) : 0.f;                                           \
    den += ex_;                                                                             \
    _Pragma("unroll") for (int c = 0; c < C; c++) acc[c] = fmaf(ex_, xs_[c], acc[c]);       \
  }

#define PCL(M) (p0 + s + ((((M) < cnt_s) ? (M) : cnt_s - 1)) * S)

template <int H, int C, int CPAD, int MODE>
__global__ void __launch_bounds__(256) edge_kernel(
    const half_t* __restrict__ xl, const float* __restrict__ xr,
    const int* __restrict__ indptr, const int* __restrict__ csrc,
    const float* __restrict__ att, const float* __restrict__ bias,
    const float* __restrict__ g, const float* __restrict__ be,
    const float* __restrict__ rm, const float* __restrict__ rv,
    float* __restrict__ out, int n) {
  constexpr int S = 4;
  constexpr int HC = H * C;
  constexpr int HCP = H * CPAD;
  constexpr int NB = CPAD / 8;  // uint4 loads per row
  int t = blockIdx.x * blockDim.x + threadIdx.x;
  if (t >= n * H * S) return;
  int grp = t >> 2;          // (node, head)
  int s = t & (S - 1);
  int node = grp / H;
  int h = grp - node * H;

  float xr_reg[C], att_reg[C];
  const float2* xrp = reinterpret_cast<const float2*>(xr + (size_t)node * HC + h * C);
#pragma unroll
  for (int i = 0; i < C / 2; i++) {
    float2 v = xrp[i];
    xr_reg[2 * i] = v.x;
    xr_reg[2 * i + 1] = v.y;
  }
#pragma unroll
  for (int c = 0; c < C; c++) att_reg[c] = att[h * C + c];

  float acc[C];
#pragma unroll
  for (int c = 0; c < C; c++) acc[c] = 0.f;
  float den = 0.f;

  int p0 = indptr[node], p1 = indptr[node + 1];
  int cnt = p1 - p0;
  int cnt_s = (cnt > s) ? ((cnt - s + S - 1) >> 2) : 0;
  const half_t* xlh = xl + h * CPAD;

  if (cnt_s > 0) {
    uint4 B0[NB], B1[NB];
    int iA = csrc[PCL(0)];
    ROW(B0, iA)
    int iB = csrc[PCL(1)];
    int m2 = ((cnt_s + 1) >> 1) << 1;
    for (int m = 0; m < m2; m += 2) {
      ROW(B1, iB)
      iA = csrc[PCL(m + 2)];
      COMP_ROW(B0, m)
      ROW(B0, iA)
      iB = csrc[PCL(m + 3)];
      COMP_ROW(B1, m + 1)
    }
  }

  // combine the S partials (group lanes are contiguous in the wave)
#pragma unroll
  for (int mask = 1; mask < S; mask <<= 1) {
    den += __shfl_xor(den, mask, 64);
#pragma unroll
    for (int c = 0; c < C; c++) acc[c] += __shfl_xor(acc[c], mask, 64);
  }
  if (s != 0) return;

  float inv = 1.f / den;
  float2* orow = reinterpret_cast<float2*>(out + (size_t)node * HC + h * C);
#pragma unroll
  for (int c2 = 0; c2 < C / 2; c2++) {
    float2 ov;
#pragma unroll
    for (int q = 0; q < 2; q++) {
      int c = 2 * c2 + q;
      float val = acc[c] * inv;
      if constexpr (MODE != 2) {
        int j = h * C + c;
        val += bias[j];
        float sc = g[j] * rsqrtf(rv[j] + BN_EPS);
        val = fmaf(sc, val - rm[j], be[j]);
        if constexpr (MODE == 1) val = (val > 0.f) ? val : expm1f(val);
      }
      if (q) ov.y = val; else ov.x = val;
    }
    orow[c2] = ov;
  }
}

// ---------------- layer-4 tail: mean over heads + bias + BN + mu/logvar heads ----------------

__global__ void final_kernel(const float* __restrict__ r4, const float* __restrict__ b4,
                             const float* __restrict__ g4, const float* __restrict__ be4,
                             const float* __restrict__ rm4, const float* __restrict__ rv4,
                             const float* __restrict__ Wmu, const float* __restrict__ bmu,
                             const float* __restrict__ Wlv, const float* __restrict__ blv,
                             float* __restrict__ out, int n) {
  int node = blockIdx.x * blockDim.x + threadIdx.x;
  if (node >= n) return;
  float hsum[10];
#pragma unroll
  for (int c = 0; c < 10; c++) hsum[c] = 0.f;
  const float* r = r4 + (size_t)node * 50;
#pragma unroll
  for (int h = 0; h < 5; h++)
#pragma unroll
    for (int c = 0; c < 10; c++) hsum[c] += r[h * 10 + c];
  float hv[10];
#pragma unroll
  for (int c = 0; c < 10; c++) {
    float v = hsum[c] * 0.2f + b4[c];
    float sc = g4[c] * rsqrtf(rv4[c] + BN_EPS);
    hv[c] = fmaf(sc, v - rm4[c], be4[c]);
  }
#pragma unroll
  for (int j = 0; j < 10; j++) {
    float mu = bmu[j], lv = blv[j];
#pragma unroll
    for (int c = 0; c < 10; c++) {
      mu = fmaf(hv[c], Wmu[c * 10 + j], mu);
      lv = fmaf(hv[c], Wlv[c * 10 + j], lv);
    }
    out[(size_t)node * 10 + j] = mu;
    out[(size_t)n * 10 + (size_t)node * 10 + j] = lv;
  }
}

// ---------------- launch ----------------

extern "C" void kernel_launch(void* const* d_in, const int* in_sizes, int n_in,
                              void* d_out, int out_size, void* d_ws, size_t ws_size,
                              hipStream_t stream) {
  const float* x = (const float*)d_in[0];
  const int* ei = (const int*)d_in[1];
  const int n = in_sizes[0] / 22;
  const int E = in_sizes[1] / 2;
  const int etot = E + n;

  auto P = [&](int i) { return (const float*)d_in[i]; };

  char* ws = (char*)d_ws;
  size_t off = 0;
  auto alloc = [&](size_t bytes) -> void* {
    void* p = ws + off;
    off += (bytes + 255) & ~(size_t)255;
    return p;
  };
  half_t* xl = (half_t*)alloc((size_t)n * 80 * 2);  // max H*CPAD = 5*16 = 80 halves
  float* xr = (float*)alloc((size_t)n * 54 * 4);
  float* hb = (float*)alloc((size_t)n * 54 * 4);
  int* deg = (int*)alloc((size_t)n * 4);
  int* indptr = (int*)alloc((size_t)(n + 1) * 4);
  ushort_t* rank = (ushort_t*)alloc((size_t)etot * 2);
  int* csrc = (int*)alloc((size_t)etot * 4);
  int nb = (n + 1023) / 1024;
  int* bsum = (int*)alloc((size_t)nb * 4);

  hipMemsetAsync(deg, 0, (size_t)n * 4, stream);
  unsigned eb = (unsigned)((etot + 255) / 256);
  unsigned nblk = (unsigned)((n + 255) / 256);
  hist_kernel<<<eb, 256, 0, stream>>>(ei, deg, rank, E, n);
  block_sum_kernel<<<(unsigned)nb, 256, 0, stream>>>(deg, bsum, n);
  scan_sums_kernel<<<1, 1024, 0, stream>>>(bsum, nb);
  scan_block_kernel<<<(unsigned)nb, 1024, 0, stream>>>(deg, bsum, indptr, n);
  place_kernel<<<eb, 256, 0, stream>>>(ei, rank, indptr, csrc, E, n);

  // layer 1: cin=22, H=3, C=18 (CPAD=24), concat, BN+ELU
  transform_kernel<22, 3, 18, 24, 6><<<(unsigned)(((size_t)n * 9 + 255) / 256), 256, 0, stream>>>(
      x, P(2), P(3), P(4), P(5), xl, xr, n);
  edge_kernel<3, 18, 24, 1><<<(unsigned)(((size_t)n * 12 + 255) / 256), 256, 0, stream>>>(
      xl, xr, indptr, csrc, P(6), P(7), P(8), P(9), P(10), P(11), hb, n);

  // layer 2: cin=54, H=3, C=14 (CPAD=16), concat, BN
  transform_kernel<54, 3, 14, 16, 6><<<(unsigned)(((size_t)n * 7 + 255) / 256), 256, 0, stream>>>(
      hb, P(12), P(13), P(14), P(15), xl, xr, n);
  edge_kernel<3, 14, 16, 0><<<(unsigned)(((size_t)n * 12 + 255) / 256), 256, 0, stream>>>(
      xl, xr, indptr, csrc, P(16), P(17), P(18), P(19), P(20), P(21), hb, n);

  // layer 3: cin=42, H=3, C=12 (CPAD=16), concat, BN
  transform_kernel<42, 3, 12, 16, 6><<<(unsigned)(((size_t)n * 6 + 255) / 256), 256, 0, stream>>>(
      hb, P(22), P(23), P(24), P(25), xl, xr, n);
  edge_kernel<3, 12, 16, 0><<<(unsigned)(((size_t)n * 12 + 255) / 256), 256, 0, stream>>>(
      xl, xr, indptr, csrc, P(26), P(27), P(28), P(29), P(30), P(31), hb, n);

  // layer 4: cin=36, H=5, C=10 (CPAD=16), mean over heads (raw; epilogue in final_kernel)
  transform_kernel<36, 5, 10, 16, 10><<<(unsigned)(((size_t)n * 5 + 255) / 256), 256, 0, stream>>>(
      hb, P(32), P(33), P(34), P(35), xl, xr, n);
  edge_kernel<5, 10, 16, 2><<<(unsigned)(((size_t)n * 20 + 255) / 256), 256, 0, stream>>>(
      xl, xr, indptr, csrc, P(36), nullptr, nullptr, nullptr, nullptr, nullptr, hb, n);

  final_kernel<<<nblk, 256, 0, stream>>>(
      hb, P(37), P(38), P(39), P(40), P(41), P(42), P(43), P(44), P(45), (float*)d_out, n);
}

// Round 7
// 578.613 us; speedup vs baseline: 1.1077x; 1.1077x over previous
//
#include <hip/hip_runtime.h>

#define BN_EPS 1e-5f

typedef _Float16 half_t;
typedef _Float16 half2_t __attribute__((ext_vector_type(2)));

#define NBK_MAX 512   // max dst-buckets (256 dsts each) -> n <= 131072
#define EPB 4096      // edges staged per block in bucket kernels

// ---------------- bucketed CSR build (no global atomics on hot paths) ----------------

// K1: count edges per 256-dst bucket (LDS histogram, flush once per block)
__global__ void __launch_bounds__(256) bucket_count_kernel(
    const int* __restrict__ ei, int* __restrict__ bcnt, int E, int etot, int nbk) {
  __shared__ int lh[NBK_MAX];
  for (int i = threadIdx.x; i < nbk; i += 256) lh[i] = 0;
  __syncthreads();
  int base = blockIdx.x * EPB;
  int cnt = min(EPB, etot - base);
  for (int i = threadIdx.x; i < cnt; i += 256) {
    int e = base + i;
    int d = (e < E) ? ei[E + e] : (e - E);
    atomicAdd(&lh[d >> 8], 1);
  }
  __syncthreads();
  for (int i = threadIdx.x; i < nbk; i += 256)
    if (lh[i]) atomicAdd(&bcnt[i], lh[i]);
}

// K2: single-block exclusive scan of bucket counts -> boff (and working copy bcur)
__global__ void __launch_bounds__(512) scan_buckets_kernel(
    const int* __restrict__ bcnt, int* __restrict__ boff, int* __restrict__ bcur,
    int nbk, int etot) {
  __shared__ int wsum[8];
  int tid = threadIdx.x, lane = tid & 63, wid = tid >> 6;
  int v = (tid < nbk) ? bcnt[tid] : 0;
  int incl = v;
#pragma unroll
  for (int off = 1; off < 64; off <<= 1) {
    int t = __shfl_up(incl, off, 64);
    if (lane >= off) incl += t;
  }
  if (lane == 63) wsum[wid] = incl;
  __syncthreads();
  if (wid == 0 && lane < 8) {
    int s = wsum[lane];
#pragma unroll
    for (int off = 1; off < 8; off <<= 1) {
      int t = __shfl_up(s, off, 8);
      if (lane >= off) s += t;
    }
    wsum[lane] = s;
  }
  __syncthreads();
  int woff = (wid > 0) ? wsum[wid - 1] : 0;
  int ex = incl + woff - v;
  if (tid < nbk) { boff[tid] = ex; bcur[tid] = ex; }
  if (tid == 0) boff[nbk] = etot;
}

// K3: scatter (src,dst) pairs into bucket-contiguous staging (LDS-staged, run writes)
__global__ void __launch_bounds__(256) bucket_scatter_kernel(
    const int* __restrict__ ei, int* __restrict__ bcur, int2* __restrict__ bstage,
    int E, int etot, int nbk) {
  __shared__ int2 se[EPB];
  __shared__ int lh[NBK_MAX], lbase[NBK_MAX];
  int base = blockIdx.x * EPB;
  int cnt = min(EPB, etot - base);
  for (int i = threadIdx.x; i < nbk; i += 256) lh[i] = 0;
  __syncthreads();
  for (int i = threadIdx.x; i < cnt; i += 256) {
    int e = base + i;
    int s, d;
    if (e < E) { s = ei[e]; d = ei[E + e]; } else { s = e - E; d = s; }
    se[i] = make_int2(s, d);
    atomicAdd(&lh[d >> 8], 1);
  }
  __syncthreads();
  for (int i = threadIdx.x; i < nbk; i += 256) {
    int c = lh[i];
    lbase[i] = c ? atomicAdd(&bcur[i], c) : 0;
    lh[i] = 0;  // becomes local run cursor
  }
  __syncthreads();
  for (int i = threadIdx.x; i < cnt; i += 256) {
    int2 sd = se[i];
    int b = sd.y >> 8;
    int r = atomicAdd(&lh[b], 1);
    bstage[lbase[b] + r] = sd;
  }
}

// K4: per-bucket degree count via LDS atomics -> coalesced deg writes
__global__ void __launch_bounds__(256) deg_count_kernel(
    const int2* __restrict__ bstage, const int* __restrict__ boff,
    int* __restrict__ deg, int n) {
  __shared__ int ld[256];
  int b = blockIdx.x;
  int d0 = b << 8;
  ld[threadIdx.x] = 0;
  __syncthreads();
  int p0 = boff[b], p1 = boff[b + 1];
  for (int p = p0 + threadIdx.x; p < p1; p += 256)
    atomicAdd(&ld[bstage[p].y - d0], 1);
  __syncthreads();
  int i = d0 + threadIdx.x;
  if (i < n) deg[i] = ld[threadIdx.x];
}

// indptr scan (3 kernels, 1024-chunks)
__global__ void __launch_bounds__(256) block_sum_kernel(const int* __restrict__ deg,
                                                        int* __restrict__ bsum, int n) {
  __shared__ int ws[4];
  int base = blockIdx.x * 1024;
  int s = 0;
  for (int i = threadIdx.x; i < 1024; i += 256) {
    int idx = base + i;
    s += (idx < n) ? deg[idx] : 0;
  }
#pragma unroll
  for (int off = 32; off; off >>= 1) s += __shfl_down(s, off, 64);
  int lane = threadIdx.x & 63, wid = threadIdx.x >> 6;
  if (lane == 0) ws[wid] = s;
  __syncthreads();
  if (threadIdx.x == 0) bsum[blockIdx.x] = ws[0] + ws[1] + ws[2] + ws[3];
}

__global__ void __launch_bounds__(1024) scan_sums_kernel(int* __restrict__ bsum, int nb) {
  __shared__ int wsum[16];
  int tid = threadIdx.x, lane = tid & 63, wid = tid >> 6;
  int v = (tid < nb) ? bsum[tid] : 0;
  int incl = v;
#pragma unroll
  for (int off = 1; off < 64; off <<= 1) {
    int t = __shfl_up(incl, off, 64);
    if (lane >= off) incl += t;
  }
  if (lane == 63) wsum[wid] = incl;
  __syncthreads();
  if (wid == 0 && lane < 16) {
    int s = wsum[lane];
#pragma unroll
    for (int off = 1; off < 16; off <<= 1) {
      int t = __shfl_up(s, off, 16);
      if (lane >= off) s += t;
    }
    wsum[lane] = s;
  }
  __syncthreads();
  int woff = (wid > 0) ? wsum[wid - 1] : 0;
  if (tid < nb) bsum[tid] = incl + woff - v;  // exclusive
}

__global__ void __launch_bounds__(1024) scan_block_kernel(const int* __restrict__ deg,
                                                          const int* __restrict__ boff,
                                                          int* __restrict__ indptr, int n) {
  __shared__ int wsum[16];
  int tid = threadIdx.x, lane = tid & 63, wid = tid >> 6;
  int i = blockIdx.x * 1024 + tid;
  int v = (i < n) ? deg[i] : 0;
  int incl = v;
#pragma unroll
  for (int off = 1; off < 64; off <<= 1) {
    int t = __shfl_up(incl, off, 64);
    if (lane >= off) incl += t;
  }
  if (lane == 63) wsum[wid] = incl;
  __syncthreads();
  if (wid == 0 && lane < 16) {
    int s = wsum[lane];
#pragma unroll
    for (int off = 1; off < 16; off <<= 1) {
      int t = __shfl_up(s, off, 16);
      if (lane >= off) s += t;
    }
    wsum[lane] = s;
  }
  __syncthreads();
  int woff = (wid > 0) ? wsum[wid - 1] : 0;
  if (i < n) indptr[i + 1] = incl + woff + boff[blockIdx.x];
  if (i == 0) indptr[0] = 0;
}

// K6: fine placement within each bucket (LDS cursors; writes confined to ~17KB window)
__global__ void __launch_bounds__(256) fine_place_kernel(
    const int2* __restrict__ bstage, const int* __restrict__ boff,
    const int* __restrict__ indptr, int* __restrict__ csrc, int n) {
  __shared__ int cur[256];
  int b = blockIdx.x;
  int d0 = b << 8;
  int i = d0 + threadIdx.x;
  cur[threadIdx.x] = (i < n) ? indptr[i] : 0;
  __syncthreads();
  int p0 = boff[b], p1 = boff[b + 1];
  for (int p = p0 + threadIdx.x; p < p1; p += 256) {
    int2 sd = bstage[p];
    int pos = atomicAdd(&cur[sd.y - d0], 1);
    csrc[pos] = sd.x;
  }
}

// ---------------- node transform ----------------
// Each thread computes JT consecutive outputs j for one node.
// xl (fp16, padded [n][H][CPAD]) = x@Wl+bl ; xr (fp32, [n][HC]) = x@Wr+br

template <int CIN, int H, int C, int CPAD, int JT>
__global__ void __launch_bounds__(256) transform_kernel(
    const float* __restrict__ x, const float* __restrict__ Wl, const float* __restrict__ Wr,
    const float* __restrict__ bl, const float* __restrict__ br, half_t* __restrict__ xl,
    float* __restrict__ xr, int n) {
  constexpr int HC = H * C;
  constexpr int TPN = HC / JT;  // threads per node
  __shared__ float sW[2 * CIN * HC];
  for (int i = threadIdx.x; i < CIN * HC; i += blockDim.x) {
    sW[i] = Wl[i];
    sW[CIN * HC + i] = Wr[i];
  }
  __syncthreads();
  int idx = blockIdx.x * blockDim.x + threadIdx.x;
  if (idx >= n * TPN) return;
  int node = idx / TPN;
  int j0 = (idx - node * TPN) * JT;

  float al[JT], ar[JT];
#pragma unroll
  for (int jj = 0; jj < JT; jj++) {
    al[jj] = bl[j0 + jj];
    ar[jj] = br[j0 + jj];
  }
  const float2* xrow = reinterpret_cast<const float2*>(x + (size_t)node * CIN);
#pragma unroll
  for (int k2 = 0; k2 < CIN / 2; k2++) {
    float2 xv = xrow[k2];
#pragma unroll
    for (int q = 0; q < 2; q++) {
      float xs = q ? xv.y : xv.x;
      int k = 2 * k2 + q;
#pragma unroll
      for (int jj = 0; jj < JT; jj++) {
        al[jj] = fmaf(xs, sW[k * HC + j0 + jj], al[jj]);
        ar[jj] = fmaf(xs, sW[CIN * HC + k * HC + j0 + jj], ar[jj]);
      }
    }
  }
#pragma unroll
  for (int jj = 0; jj < JT; jj++) {
    int j = j0 + jj;
    int h = j / C, c = j - h * C;
    xl[((size_t)node * H + h) * CPAD + c] = (half_t)al[jj];
    xr[(size_t)node * HC + j] = ar[jj];
  }
}

// ---------------- fused edge pass ----------------
// One thread per (node, head). CSR gather of padded fp16 rows via uint4 loads.
// 3-deep row pipeline + 3-index register queue loaded 2 iterations ahead.
// MODE 0: +bias,BN  1: +bias,BN,ELU  2: raw

#define IDX(K) csrc[p0 + (((K) < cnt) ? (K) : cnt - 1)]

#define ROW(B, IR)                                                                \
  {                                                                               \
    const uint4* xp_ = reinterpret_cast<const uint4*>(xlh + (size_t)(IR) * HCP);  \
    _Pragma("unroll") for (int i_ = 0; i_ < NB; i_++) B[i_] = xp_[i_];            \
  }

#define COMP_ROW(B, M)                                                                      \
  {                                                                                         \
    const half2_t* hp_ = reinterpret_cast<const half2_t*>(B);                               \
    float xs_[C];                                                                           \
    _Pragma("unroll") for (int i = 0; i < C / 2; i++) {                                     \
      xs_[2 * i] = (float)hp_[i].x;                                                         \
      xs_[2 * i + 1] = (float)hp_[i].y;                                                     \
    }                                                                                       \
    float e_ = 0.f;                                                                         \
    _Pragma("unroll") for (int c = 0; c < C; c++) {                                         \
      float m_ = xs_[c] + xr_reg[c];                                                        \
      m_ = (m_ > 0.f) ? m_ : 0.2f * m_;                                                     \
      e_ = fmaf(att_reg[c], m_, e_);                                                        \
    }                                                                                       \
    float ex_ = ((M) < cnt) ? __expf(e_) : 0.f;                                             \
    den += ex_;                                                                             \
    _Pragma("unroll") for (int c = 0; c < C; c++) acc[c] = fmaf(ex_, xs_[c], acc[c]);       \
  }

template <int H, int C, int CPAD, int MODE>
__global__ void __launch_bounds__(256) edge_kernel(
    const half_t* __restrict__ xl, const float* __restrict__ xr,
    const int* __restrict__ indptr, const int* __restrict__ csrc,
    const float* __restrict__ att, const float* __restrict__ bias,
    const float* __restrict__ g, const float* __restrict__ be,
    const float* __restrict__ rm, const float* __restrict__ rv,
    float* __restrict__ out, int n) {
  constexpr int HC = H * C;
  constexpr int HCP = H * CPAD;
  constexpr int NB = CPAD / 8;  // uint4 loads per row
  int t = blockIdx.x * blockDim.x + threadIdx.x;
  if (t >= n * H) return;
  int node = t / H;
  int h = t - node * H;

  float xr_reg[C], att_reg[C];
  const float2* xrp = reinterpret_cast<const float2*>(xr + (size_t)node * HC + h * C);
#pragma unroll
  for (int i = 0; i < C / 2; i++) {
    float2 v = xrp[i];
    xr_reg[2 * i] = v.x;
    xr_reg[2 * i + 1] = v.y;
  }
#pragma unroll
  for (int c = 0; c < C; c++) att_reg[c] = att[h * C + c];

  float acc[C];
#pragma unroll
  for (int c = 0; c < C; c++) acc[c] = 0.f;
  float den = 0.f;

  int p0 = indptr[node], p1 = indptr[node + 1];
  int cnt = p1 - p0;
  const half_t* xlh = xl + h * CPAD;

  uint4 B0[NB], B1[NB], B2[NB];
  int i0, i1, i2;
  i0 = IDX(0); i1 = IDX(1); i2 = IDX(2);
  ROW(B0, i0) ROW(B1, i1) ROW(B2, i2)
  i0 = IDX(3); i1 = IDX(4); i2 = IDX(5);
  int cnt3 = ((cnt + 2) / 3) * 3;
  for (int m = 0; m < cnt3; m += 3) {
    COMP_ROW(B0, m)     ROW(B0, i0) i0 = IDX(m + 6);
    COMP_ROW(B1, m + 1) ROW(B1, i1) i1 = IDX(m + 7);
    COMP_ROW(B2, m + 2) ROW(B2, i2) i2 = IDX(m + 8);
  }

  float inv = 1.f / den;
  float2* orow = reinterpret_cast<float2*>(out + (size_t)node * HC + h * C);
#pragma unroll
  for (int c2 = 0; c2 < C / 2; c2++) {
    float2 ov;
#pragma unroll
    for (int q = 0; q < 2; q++) {
      int c = 2 * c2 + q;
      float val = acc[c] * inv;
      if constexpr (MODE != 2) {
        int j = h * C + c;
        val += bias[j];
        float sc = g[j] * rsqrtf(rv[j] + BN_EPS);
        val = fmaf(sc, val - rm[j], be[j]);
        if constexpr (MODE == 1) val = (val > 0.f) ? val : expm1f(val);
      }
      if (q) ov.y = val; else ov.x = val;
    }
    orow[c2] = ov;
  }
}

// ---------------- layer-4 tail: mean over heads + bias + BN + mu/logvar heads ----------------

__global__ void final_kernel(const float* __restrict__ r4, const float* __restrict__ b4,
                             const float* __restrict__ g4, const float* __restrict__ be4,
                             const float* __restrict__ rm4, const float* __restrict__ rv4,
                             const float* __restrict__ Wmu, const float* __restrict__ bmu,
                             const float* __restrict__ Wlv, const float* __restrict__ blv,
                             float* __restrict__ out, int n) {
  int node = blockIdx.x * blockDim.x + threadIdx.x;
  if (node >= n) return;
  float hsum[10];
#pragma unroll
  for (int c = 0; c < 10; c++) hsum[c] = 0.f;
  const float* r = r4 + (size_t)node * 50;
#pragma unroll
  for (int h = 0; h < 5; h++)
#pragma unroll
    for (int c = 0; c < 10; c++) hsum[c] += r[h * 10 + c];
  float hv[10];
#pragma unroll
  for (int c = 0; c < 10; c++) {
    float v = hsum[c] * 0.2f + b4[c];
    float sc = g4[c] * rsqrtf(rv4[c] + BN_EPS);
    hv[c] = fmaf(sc, v - rm4[c], be4[c]);
  }
#pragma unroll
  for (int j = 0; j < 10; j++) {
    float mu = bmu[j], lv = blv[j];
#pragma unroll
    for (int c = 0; c < 10; c++) {
      mu = fmaf(hv[c], Wmu[c * 10 + j], mu);
      lv = fmaf(hv[c], Wlv[c * 10 + j], lv);
    }
    out[(size_t)node * 10 + j] = mu;
    out[(size_t)n * 10 + (size_t)node * 10 + j] = lv;
  }
}

// ---------------- launch ----------------

extern "C" void kernel_launch(void* const* d_in, const int* in_sizes, int n_in,
                              void* d_out, int out_size, void* d_ws, size_t ws_size,
                              hipStream_t stream) {
  const float* x = (const float*)d_in[0];
  const int* ei = (const int*)d_in[1];
  const int n = in_sizes[0] / 22;
  const int E = in_sizes[1] / 2;
  const int etot = E + n;
  const int nbk = (n + 255) >> 8;  // 256-dst buckets

  auto P = [&](int i) { return (const float*)d_in[i]; };

  char* ws = (char*)d_ws;
  size_t off = 0;
  auto alloc = [&](size_t bytes) -> void* {
    void* p = ws + off;
    off += (bytes + 255) & ~(size_t)255;
    return p;
  };
  half_t* xl = (half_t*)alloc((size_t)n * 80 * 2);  // max H*CPAD = 5*16 = 80 halves
  float* xr = (float*)alloc((size_t)n * 54 * 4);
  float* hb = (float*)alloc((size_t)n * 54 * 4);
  int* deg = (int*)alloc((size_t)n * 4);
  int* indptr = (int*)alloc((size_t)(n + 1) * 4);
  int* csrc = (int*)alloc((size_t)etot * 4);
  int* bcnt = (int*)alloc((size_t)(nbk + 1) * 4);
  int* boff = (int*)alloc((size_t)(nbk + 1) * 4);
  int* bcur = (int*)alloc((size_t)(nbk + 1) * 4);
  int nb = (n + 1023) / 1024;
  int* bsum = (int*)alloc((size_t)nb * 4);
  // bstage aliases xl/xr (only live before transforms run; same-stream ordering)
  int2* bstage = (int2*)xl;

  unsigned bb = (unsigned)((etot + EPB - 1) / EPB);
  unsigned nblk = (unsigned)((n + 255) / 256);

  hipMemsetAsync(bcnt, 0, (size_t)(nbk + 1) * 4, stream);
  bucket_count_kernel<<<bb, 256, 0, stream>>>(ei, bcnt, E, etot, nbk);
  scan_buckets_kernel<<<1, 512, 0, stream>>>(bcnt, boff, bcur, nbk, etot);
  bucket_scatter_kernel<<<bb, 256, 0, stream>>>(ei, bcur, bstage, E, etot, nbk);
  deg_count_kernel<<<(unsigned)nbk, 256, 0, stream>>>(bstage, boff, deg, n);
  block_sum_kernel<<<(unsigned)nb, 256, 0, stream>>>(deg, bsum, n);
  scan_sums_kernel<<<1, 1024, 0, stream>>>(bsum, nb);
  scan_block_kernel<<<(unsigned)nb, 1024, 0, stream>>>(deg, bsum, indptr, n);
  fine_place_kernel<<<(unsigned)nbk, 256, 0, stream>>>(bstage, boff, indptr, csrc, n);

  // layer 1: cin=22, H=3, C=18 (CPAD=24), concat, BN+ELU
  transform_kernel<22, 3, 18, 24, 6><<<(unsigned)(((size_t)n * 9 + 255) / 256), 256, 0, stream>>>(
      x, P(2), P(3), P(4), P(5), xl, xr, n);
  edge_kernel<3, 18, 24, 1><<<(unsigned)(((size_t)n * 3 + 255) / 256), 256, 0, stream>>>(
      xl, xr, indptr, csrc, P(6), P(7), P(8), P(9), P(10), P(11), hb, n);

  // layer 2: cin=54, H=3, C=14 (CPAD=16), concat, BN
  transform_kernel<54, 3, 14, 16, 6><<<(unsigned)(((size_t)n * 7 + 255) / 256), 256, 0, stream>>>(
      hb, P(12), P(13), P(14), P(15), xl, xr, n);
  edge_kernel<3, 14, 16, 0><<<(unsigned)(((size_t)n * 3 + 255) / 256), 256, 0, stream>>>(
      xl, xr, indptr, csrc, P(16), P(17), P(18), P(19), P(20), P(21), hb, n);

  // layer 3: cin=42, H=3, C=12 (CPAD=16), concat, BN
  transform_kernel<42, 3, 12, 16, 6><<<(unsigned)(((size_t)n * 6 + 255) / 256), 256, 0, stream>>>(
      hb, P(22), P(23), P(24), P(25), xl, xr, n);
  edge_kernel<3, 12, 16, 0><<<(unsigned)(((size_t)n * 3 + 255) / 256), 256, 0, stream>>>(
      xl, xr, indptr, csrc, P(26), P(27), P(28), P(29), P(30), P(31), hb, n);

  // layer 4: cin=36, H=5, C=10 (CPAD=16), mean over heads (raw; epilogue in final_kernel)
  transform_kernel<36, 5, 10, 16, 10><<<(unsigned)(((size_t)n * 5 + 255) / 256), 256, 0, stream>>>(
      hb, P(32), P(33), P(34), P(35), xl, xr, n);
  edge_kernel<5, 10, 16, 2><<<(unsigned)(((size_t)n * 5 + 255) / 256), 256, 0, stream>>>(
      xl, xr, indptr, csrc, P(36), nullptr, nullptr, nullptr, nullptr, nullptr, hb, n);

  final_kernel<<<nblk, 256, 0, stream>>>(
      hb, P(37), P(38), P(39), P(40), P(41), P(42), P(43), P(44), P(45), (float*)d_out, n);
}